// Round 4
// baseline (356.778 us; speedup 1.0000x reference)
//
#include <hip/hip_runtime.h>
#include <hip/hip_bf16.h>

// 25-level wavelet decomposition, f: 2^25 f32, P: [25,2] f32.
// out layout: out[0]=final approx; detail level j occupies [2^(24-j), 2^(25-j)).
//
// Single fused kernel. Each block owns a contiguous chunk of 2^14 elements:
//   levels 0-2 in registers (details written coalesced),
//   levels 3-13 via LDS ping-pong (12 KB -> 8 blocks/CU).
// Block's level-13 approx -> out[blk] (agent-scope store; [0,2048) is temp,
// fully rewritten by the tail). Last block to finish (atomic counter in d_ws)
// runs levels 14-18 in LDS and 19-24 in one wave via shuffles.
//
// NOTE (R3 post-mortem): non-temporal stores on gfx950 collapsed write BW
// (465us vs 82us) -- plain stores only.

#define CHUNK 16384
#define THREADS 256
#define NBLOCKS ((1 << 25) / CHUNK)   // 2048

__device__ __forceinline__ void level_params(const float* __restrict__ P, int j,
                                             float& hx, float& hy) {
    float px = P[2 * j], py = P[2 * j + 1];
    float n = fmaxf(sqrtf(px * px + py * py), 1e-12f);
    hx = px / n;  // phi_x
    hy = py / n;  // phi_y   (psi = (phi_y, -phi_x))
}

__global__ __launch_bounds__(THREADS, 8)
void wave_fused(const float* __restrict__ f, const float* __restrict__ P,
                float* __restrict__ out, unsigned* __restrict__ counter) {
    __shared__ float A[CHUNK / 8];   // 2048 floats, 8 KB
    __shared__ float B[CHUNK / 16];  // 1024 floats, 4 KB
    __shared__ unsigned last;
    const int tid = threadIdx.x;
    const int blk = blockIdx.x;

    float hx0, hy0, hx1, hy1, hx2, hy2;
    level_params(P, 0, hx0, hy0);
    level_params(P, 1, hx1, hy1);
    level_params(P, 2, hx2, hy2);

    // ---- levels 0..2 in registers: 8 consecutive elements per thread-iter ----
    const float4* in4 = reinterpret_cast<const float4*>(f) + (size_t)blk * (CHUNK / 4);
    float4* d0out = reinterpret_cast<float4*>(out + (1 << 24) + (size_t)blk * (CHUNK / 2));
    float2* d1out = reinterpret_cast<float2*>(out + (1 << 23) + (size_t)blk * (CHUNK / 4));
    float*  d2out = out + (1 << 22) + (size_t)blk * (CHUNK / 8);

#pragma unroll 4
    for (int t = 0; t < CHUNK / 8 / THREADS; ++t) {   // 8 iters
        int g = tid + t * THREADS;                    // group of 8 elements
        float4 u = in4[2 * g];
        float4 v = in4[2 * g + 1];
        // level 0
        float d0 = u.x * hy0 - u.y * hx0, a0 = u.x * hx0 + u.y * hy0;
        float d1 = u.z * hy0 - u.w * hx0, a1 = u.z * hx0 + u.w * hy0;
        float d2 = v.x * hy0 - v.y * hx0, a2 = v.x * hx0 + v.y * hy0;
        float d3 = v.z * hy0 - v.w * hx0, a3 = v.z * hx0 + v.w * hy0;
        d0out[g] = make_float4(d0, d1, d2, d3);
        // level 1
        float e0 = a0 * hy1 - a1 * hx1, b0 = a0 * hx1 + a1 * hy1;
        float e1 = a2 * hy1 - a3 * hx1, b1 = a2 * hx1 + a3 * hy1;
        d1out[g] = make_float2(e0, e1);
        // level 2
        d2out[g] = b0 * hy2 - b1 * hx2;
        A[g] = b0 * hx2 + b1 * hy2;
    }
    __syncthreads();

    // ---- levels 3..13: LDS ping-pong (2048 -> 1) ----
    float* cur = A;
    float* nxt = B;
    for (int j = 3; j <= 13; ++j) {
        int p = CHUNK >> (j + 1);    // pairs: j=3 -> 1024 ... j=13 -> 1
        float hx, hy;
        level_params(P, j, hx, hy);
        float* dout = out + (1 << (24 - j)) + (size_t)blk * p;
        for (int k = tid; k < p; k += THREADS) {
            float x = cur[2 * k], y = cur[2 * k + 1];
            dout[k] = x * hy - y * hx;
            nxt[k] = x * hx + y * hy;
        }
        __syncthreads();
        float* tmp = cur; cur = nxt; nxt = tmp;
    }

    // publish level-13 approx to temp slot out[blk] (agent-scope visible)
    if (tid == 0) {
        __hip_atomic_store(&out[blk], cur[0], __ATOMIC_RELAXED,
                           __HIP_MEMORY_SCOPE_AGENT);
    }
    __threadfence();                       // release: approx visible before count
    if (tid == 0) last = atomicAdd(counter, 1u);
    __syncthreads();
    if (last != NBLOCKS - 1) return;       // not the last block

    // ---- tail: last block runs levels 14..24 on the 2048 approx values ----
    __threadfence();                       // acquire: see other blocks' stores
    for (int k = tid; k < NBLOCKS; k += THREADS) {
        A[k] = __hip_atomic_load(&out[k], __ATOMIC_RELAXED,
                                 __HIP_MEMORY_SCOPE_AGENT);
    }
    __syncthreads();

    cur = A; nxt = B;
    for (int j = 14; j <= 18; ++j) {       // 1024 .. 64 pairs
        int p = 1 << (24 - j);
        float hx, hy;
        level_params(P, j, hx, hy);
        float* dout = out + p;             // detail band [p, 2p)
        for (int k = tid; k < p; k += THREADS) {
            float x = cur[2 * k], y = cur[2 * k + 1];
            dout[k] = x * hy - y * hx;
            nxt[k] = x * hx + y * hy;
        }
        __syncthreads();
        float* tmp = cur; cur = nxt; nxt = tmp;
    }

    // levels 19..24 (32 pairs .. 1 pair) in wave 0 via shuffles
    if (tid < 64) {
        float v = cur[tid];                // 64 remaining values, 1/lane
        for (int j = 19; j <= 24; ++j) {
            int p = 1 << (24 - j);         // 32,16,8,4,2,1
            float hx, hy;
            level_params(P, j, hx, hy);
            float x = __shfl(v, 2 * tid, 64);
            float y = __shfl(v, 2 * tid + 1, 64);
            if (tid < p) out[p + tid] = x * hy - y * hx;
            v = x * hx + y * hy;
        }
        if (tid == 0) out[0] = v;
    }
}

extern "C" void kernel_launch(void* const* d_in, const int* in_sizes, int n_in,
                              void* d_out, int out_size, void* d_ws, size_t ws_size,
                              hipStream_t stream) {
    const float* f = (const float*)d_in[0];
    const float* P = (const float*)d_in[1];
    float* out = (float*)d_out;
    unsigned* counter = (unsigned*)d_ws;

    hipMemsetAsync(counter, 0, sizeof(unsigned), stream);
    wave_fused<<<NBLOCKS, THREADS, 0, stream>>>(f, P, out, counter);
}

// Round 5
// 64.442 us; speedup vs baseline: 5.5364x; 5.5364x over previous
//
#include <hip/hip_runtime.h>
#include <hip/hip_bf16.h>

// 25-level wavelet decomposition, f: 2^25 f32, P: [25,2] f32.
// out layout: out[0]=final approx; detail level j occupies [2^(24-j), 2^(25-j)).
//
// Single fused kernel. Each block owns a contiguous chunk of 2^14 elements:
//   levels 0-2 in registers (details written coalesced),
//   levels 3-13 via LDS ping-pong (12 KB -> 8 blocks/CU).
// Block's level-13 approx -> out[blk] via relaxed agent-scope atomic store
// (sc1: bypasses the non-coherent per-XCD L2, lands at the coherent point).
// tid0 then waits vmcnt(0) (its own wave only) and bumps a counter in d_ws
// with a relaxed agent-scope fetch_add. The last block runs levels 14-24.
//
// HISTORY:
//  R3: non-temporal stores suspected -> reverted, NO effect (465->466us).
//  R4: real culprit was __threadfence() by all threads: agent seq_cst fence
//      on gfx950 emits L2 writeback+invalidate (per-XCD L2 non-coherent);
//      ~16K full-L2 maintenance ops serialized at TCC. Replaced with
//      tid0-only {sc1 store -> s_waitcnt vmcnt(0) -> relaxed fetch_add}:
//      no L2 writeback, no invalidate anywhere.

#define CHUNK 16384
#define THREADS 256
#define NBLOCKS ((1 << 25) / CHUNK)   // 2048

__device__ __forceinline__ void level_params(const float* __restrict__ P, int j,
                                             float& hx, float& hy) {
    float px = P[2 * j], py = P[2 * j + 1];
    float n = fmaxf(sqrtf(px * px + py * py), 1e-12f);
    hx = px / n;  // phi_x
    hy = py / n;  // phi_y   (psi = (phi_y, -phi_x))
}

__global__ __launch_bounds__(THREADS, 8)
void wave_fused(const float* __restrict__ f, const float* __restrict__ P,
                float* __restrict__ out, unsigned* __restrict__ counter) {
    __shared__ float A[CHUNK / 8];   // 2048 floats, 8 KB
    __shared__ float B[CHUNK / 16];  // 1024 floats, 4 KB
    __shared__ unsigned last;
    const int tid = threadIdx.x;
    const int blk = blockIdx.x;

    float hx0, hy0, hx1, hy1, hx2, hy2;
    level_params(P, 0, hx0, hy0);
    level_params(P, 1, hx1, hy1);
    level_params(P, 2, hx2, hy2);

    // ---- levels 0..2 in registers: 8 consecutive elements per thread-iter ----
    const float4* in4 = reinterpret_cast<const float4*>(f) + (size_t)blk * (CHUNK / 4);
    float4* d0out = reinterpret_cast<float4*>(out + (1 << 24) + (size_t)blk * (CHUNK / 2));
    float2* d1out = reinterpret_cast<float2*>(out + (1 << 23) + (size_t)blk * (CHUNK / 4));
    float*  d2out = out + (1 << 22) + (size_t)blk * (CHUNK / 8);

#pragma unroll 4
    for (int t = 0; t < CHUNK / 8 / THREADS; ++t) {   // 8 iters
        int g = tid + t * THREADS;                    // group of 8 elements
        float4 u = in4[2 * g];
        float4 v = in4[2 * g + 1];
        // level 0
        float d0 = u.x * hy0 - u.y * hx0, a0 = u.x * hx0 + u.y * hy0;
        float d1 = u.z * hy0 - u.w * hx0, a1 = u.z * hx0 + u.w * hy0;
        float d2 = v.x * hy0 - v.y * hx0, a2 = v.x * hx0 + v.y * hy0;
        float d3 = v.z * hy0 - v.w * hx0, a3 = v.z * hx0 + v.w * hy0;
        d0out[g] = make_float4(d0, d1, d2, d3);
        // level 1
        float e0 = a0 * hy1 - a1 * hx1, b0 = a0 * hx1 + a1 * hy1;
        float e1 = a2 * hy1 - a3 * hx1, b1 = a2 * hx1 + a3 * hy1;
        d1out[g] = make_float2(e0, e1);
        // level 2
        d2out[g] = b0 * hy2 - b1 * hx2;
        A[g] = b0 * hx2 + b1 * hy2;
    }
    __syncthreads();

    // ---- levels 3..13: LDS ping-pong (2048 -> 1) ----
    float* cur = A;
    float* nxt = B;
    for (int j = 3; j <= 13; ++j) {
        int p = CHUNK >> (j + 1);    // pairs: j=3 -> 1024 ... j=13 -> 1
        float hx, hy;
        level_params(P, j, hx, hy);
        float* dout = out + (1 << (24 - j)) + (size_t)blk * p;
        for (int k = tid; k < p; k += THREADS) {
            float x = cur[2 * k], y = cur[2 * k + 1];
            dout[k] = x * hy - y * hx;
            nxt[k] = x * hx + y * hy;
        }
        __syncthreads();
        float* tmp = cur; cur = nxt; nxt = tmp;
    }

    // ---- publish level-13 approx; fence-free last-block election ----
    if (tid == 0) {
        __hip_atomic_store(&out[blk], cur[0], __ATOMIC_RELAXED,
                           __HIP_MEMORY_SCOPE_AGENT);
        // Wait for THIS wave's outstanding VMEM (incl. the sc1 store above,
        // which lands at the coherent point) -- no L2 writeback/invalidate.
        asm volatile("s_waitcnt vmcnt(0)" ::: "memory");
        last = __hip_atomic_fetch_add(counter, 1u, __ATOMIC_RELAXED,
                                      __HIP_MEMORY_SCOPE_AGENT);
    }
    __syncthreads();
    if (last != NBLOCKS - 1) return;       // not the last block

    // ---- tail: last block runs levels 14..24 on the 2048 approx values ----
    // (loads are agent-scope sc1: read the coherent point, no stale L1/L2;
    //  ordered behind the data-dependent branch on `last`)
    for (int k = tid; k < NBLOCKS; k += THREADS) {
        A[k] = __hip_atomic_load(&out[k], __ATOMIC_RELAXED,
                                 __HIP_MEMORY_SCOPE_AGENT);
    }
    __syncthreads();

    cur = A; nxt = B;
    for (int j = 14; j <= 18; ++j) {       // 1024 .. 64 pairs
        int p = 1 << (24 - j);
        float hx, hy;
        level_params(P, j, hx, hy);
        float* dout = out + p;             // detail band [p, 2p)
        for (int k = tid; k < p; k += THREADS) {
            float x = cur[2 * k], y = cur[2 * k + 1];
            dout[k] = x * hy - y * hx;
            nxt[k] = x * hx + y * hy;
        }
        __syncthreads();
        float* tmp = cur; cur = nxt; nxt = tmp;
    }

    // levels 19..24 (32 pairs .. 1 pair) in wave 0 via shuffles
    if (tid < 64) {
        float v = cur[tid];                // 64 remaining values, 1/lane
        for (int j = 19; j <= 24; ++j) {
            int p = 1 << (24 - j);         // 32,16,8,4,2,1
            float hx, hy;
            level_params(P, j, hx, hy);
            float x = __shfl(v, 2 * tid, 64);
            float y = __shfl(v, 2 * tid + 1, 64);
            if (tid < p) out[p + tid] = x * hy - y * hx;
            v = x * hx + y * hy;
        }
        if (tid == 0) out[0] = v;
    }
}

extern "C" void kernel_launch(void* const* d_in, const int* in_sizes, int n_in,
                              void* d_out, int out_size, void* d_ws, size_t ws_size,
                              hipStream_t stream) {
    const float* f = (const float*)d_in[0];
    const float* P = (const float*)d_in[1];
    float* out = (float*)d_out;
    unsigned* counter = (unsigned*)d_ws;

    hipMemsetAsync(counter, 0, sizeof(unsigned), stream);
    wave_fused<<<NBLOCKS, THREADS, 0, stream>>>(f, P, out, counter);
}

// Round 6
// 52.594 us; speedup vs baseline: 6.7837x; 1.2253x over previous
//
#include <hip/hip_runtime.h>
#include <hip/hip_bf16.h>

// 25-level wavelet decomposition, f: 2^25 f32, P: [25,2] f32.
// out layout: out[0]=final approx; detail level j occupies [2^(24-j), 2^(25-j)).
//
// Two kernels (R5: fused single-kernel reverted -- all 2048 blocks are
// co-resident, so the last-block election serialized 2048 same-address
// atomics with the whole GPU idle; a second 1-block launch is cheaper).
//
// Kernel 1: each block owns a contiguous chunk of 2^14 elements.
//   Levels 0-2 in registers straight off float4 loads; detail bands written
//   with NON-TEMPORAL stores (evict-first hint: detail data is write-once,
//   never device-read -> keep the 128 MB input L3-resident across graph
//   replays instead; R2/R3 never isolated nt without the fence).
//   Only the level-2 approx (2048 floats) goes to LDS; levels 3-13 ping-pong
//   in 12 KB LDS -> 8 blocks/CU. Level-13 approx -> out[blk] (temp, region
//   [0,2048) fully rewritten by kernel 2).
// Kernel 2: single block finishes levels 14-24.
//
// HISTORY:
//  R3/R4: 465us regression was __threadfence() (agent fence => per-XCD L2
//         writeback/invalidate storm), NOT nt stores (untested alone).
//  R4: fused last-block election = +10us vs split (atomic burst, idle tail).

#define CHUNK 16384
#define THREADS 256
#define NBLOCKS ((1 << 25) / CHUNK)   // 2048

typedef __attribute__((ext_vector_type(4))) float f4_t;
typedef __attribute__((ext_vector_type(2))) float f2_t;

__device__ __forceinline__ void nt_store4(float4 v, float4* p) {
    f4_t t = {v.x, v.y, v.z, v.w};
    __builtin_nontemporal_store(t, (f4_t*)p);
}
__device__ __forceinline__ void nt_store2(float2 v, float2* p) {
    f2_t t = {v.x, v.y};
    __builtin_nontemporal_store(t, (f2_t*)p);
}
__device__ __forceinline__ void nt_store1(float v, float* p) {
    __builtin_nontemporal_store(v, p);
}

__device__ __forceinline__ void level_params(const float* __restrict__ P, int j,
                                             float& hx, float& hy) {
    float px = P[2 * j], py = P[2 * j + 1];
    float n = fmaxf(sqrtf(px * px + py * py), 1e-12f);
    hx = px / n;  // phi_x
    hy = py / n;  // phi_y   (psi = (phi_y, -phi_x))
}

__global__ __launch_bounds__(THREADS, 8)
void wave_lvl0_13(const float* __restrict__ f, const float* __restrict__ P,
                  float* __restrict__ out) {
    __shared__ float A[CHUNK / 8];   // 2048 floats, 8 KB
    __shared__ float B[CHUNK / 16];  // 1024 floats, 4 KB
    const int tid = threadIdx.x;
    const int blk = blockIdx.x;

    float hx0, hy0, hx1, hy1, hx2, hy2;
    level_params(P, 0, hx0, hy0);
    level_params(P, 1, hx1, hy1);
    level_params(P, 2, hx2, hy2);

    // ---- levels 0..2 in registers: 8 consecutive elements per thread-iter ----
    const float4* in4 = reinterpret_cast<const float4*>(f) + (size_t)blk * (CHUNK / 4);
    float4* d0out = reinterpret_cast<float4*>(out + (1 << 24) + (size_t)blk * (CHUNK / 2));
    float2* d1out = reinterpret_cast<float2*>(out + (1 << 23) + (size_t)blk * (CHUNK / 4));
    float*  d2out = out + (1 << 22) + (size_t)blk * (CHUNK / 8);

#pragma unroll 4
    for (int t = 0; t < CHUNK / 8 / THREADS; ++t) {   // 8 iters
        int g = tid + t * THREADS;                    // group of 8 elements
        float4 u = in4[2 * g];
        float4 v = in4[2 * g + 1];
        // level 0
        float d0 = u.x * hy0 - u.y * hx0, a0 = u.x * hx0 + u.y * hy0;
        float d1 = u.z * hy0 - u.w * hx0, a1 = u.z * hx0 + u.w * hy0;
        float d2 = v.x * hy0 - v.y * hx0, a2 = v.x * hx0 + v.y * hy0;
        float d3 = v.z * hy0 - v.w * hx0, a3 = v.z * hx0 + v.w * hy0;
        nt_store4(make_float4(d0, d1, d2, d3), &d0out[g]);
        // level 1
        float e0 = a0 * hy1 - a1 * hx1, b0 = a0 * hx1 + a1 * hy1;
        float e1 = a2 * hy1 - a3 * hx1, b1 = a2 * hx1 + a3 * hy1;
        nt_store2(make_float2(e0, e1), &d1out[g]);
        // level 2
        nt_store1(b0 * hy2 - b1 * hx2, &d2out[g]);
        A[g] = b0 * hx2 + b1 * hy2;
    }
    __syncthreads();

    // ---- levels 3..13: LDS ping-pong (2048 -> 1) ----
    float* cur = A;
    float* nxt = B;
    for (int j = 3; j <= 13; ++j) {
        int p = CHUNK >> (j + 1);    // pairs: j=3 -> 1024 ... j=13 -> 1
        float hx, hy;
        level_params(P, j, hx, hy);
        float* dout = out + (1 << (24 - j)) + (size_t)blk * p;
        for (int k = tid; k < p; k += THREADS) {
            float x = cur[2 * k], y = cur[2 * k + 1];
            nt_store1(x * hy - y * hx, &dout[k]);
            nxt[k] = x * hx + y * hy;
        }
        __syncthreads();
        float* tmp = cur; cur = nxt; nxt = tmp;
    }

    if (tid == 0) out[blk] = cur[0];
}

__global__ __launch_bounds__(THREADS)
void wave_lvl14_24(const float* __restrict__ P, float* __restrict__ out) {
    __shared__ float A[NBLOCKS];      // 2048
    __shared__ float B[NBLOCKS / 2];  // 1024
    const int tid = threadIdx.x;

    for (int k = tid; k < NBLOCKS; k += THREADS) A[k] = out[k];
    __syncthreads();

    float* cur = A;
    float* nxt = B;
    for (int j = 14; j <= 18; ++j) {  // 1024 .. 64 pairs
        int p = 1 << (24 - j);
        float hx, hy;
        level_params(P, j, hx, hy);
        float* dout = out + p;        // detail band [p, 2p)
        for (int k = tid; k < p; k += THREADS) {
            float x = cur[2 * k], y = cur[2 * k + 1];
            dout[k] = x * hy - y * hx;
            nxt[k]  = x * hx + y * hy;
        }
        __syncthreads();
        float* tmp = cur; cur = nxt; nxt = tmp;
    }

    // levels 19..24 (32 pairs .. 1 pair) in wave 0 via shuffles
    if (tid < 64) {
        float v = cur[tid];           // 64 remaining values, 1/lane
        for (int j = 19; j <= 24; ++j) {
            int p = 1 << (24 - j);    // 32,16,8,4,2,1
            float hx, hy;
            level_params(P, j, hx, hy);
            float x = __shfl(v, 2 * tid, 64);
            float y = __shfl(v, 2 * tid + 1, 64);
            if (tid < p) out[p + tid] = x * hy - y * hx;
            v = x * hx + y * hy;
        }
        if (tid == 0) out[0] = v;
    }
}

extern "C" void kernel_launch(void* const* d_in, const int* in_sizes, int n_in,
                              void* d_out, int out_size, void* d_ws, size_t ws_size,
                              hipStream_t stream) {
    const float* f = (const float*)d_in[0];
    const float* P = (const float*)d_in[1];
    float* out = (float*)d_out;

    wave_lvl0_13<<<NBLOCKS, THREADS, 0, stream>>>(f, P, out);
    wave_lvl14_24<<<1, THREADS, 0, stream>>>(P, out);
}